// Round 2
// 599.004 us; speedup vs baseline: 1.1069x; 1.1069x over previous
//
#include <hip/hip_runtime.h>

#define NN     10000
#define HEADS  8
#define HID    64
#define ODIM   5000
#define NE     160000
#define ET     170000   // NE + NN self-loops
#define NEG    0.2f
#define WT_LD  5120     // padded leading dim of transposed fc_w
#define TRB    79       // ceil(ODIM/64) transpose blocks
#define DEGB   40       // ceil(NN/256) deg-init blocks
#define PREPB  (TRB + DEGB + 1)
#define FC_R   16       // fc2 rows per block

// -------- edge_index storage-format detection (int32 vs int64 words) --------
__device__ __forceinline__ int ld_idx(const int* ei, int k, int mode) {
    return mode ? ei[2 * k] : ei[k];   // little-endian lo word carries the id
}

// prep: fc_w transpose (blocks 0..TRB-1), deg init (TRB..TRB+DEGB-1), detect (last)
__global__ void __launch_bounds__(256) k_prep(
    const int* __restrict__ ei, int* __restrict__ flag,
    int* __restrict__ deg,
    const float* __restrict__ W, float* __restrict__ Wt) {
    __shared__ float T[64][65];
    __shared__ int nz;
    int bid = blockIdx.x, t = threadIdx.x;
    if (bid < TRB) {
        int c0 = bid * 64;
        int cl = t >> 2, kq = (t & 3) * 16;
        if (c0 + cl < ODIM) {
            #pragma unroll
            for (int q = 0; q < 4; q++) {
                float4 v = *(const float4*)(W + (size_t)(c0 + cl) * 64 + kq + q * 4);
                T[cl][kq + q * 4 + 0] = v.x;
                T[cl][kq + q * 4 + 1] = v.y;
                T[cl][kq + q * 4 + 2] = v.z;
                T[cl][kq + q * 4 + 3] = v.w;
            }
        } else {
            #pragma unroll
            for (int q = 0; q < 16; q++) T[cl][kq + q] = 0.f;   // zero pad cols
        }
        __syncthreads();
        int kl = t >> 2, cq = (t & 3) * 16;
        #pragma unroll
        for (int q = 0; q < 4; q++) {
            float4 v = make_float4(T[cq + q * 4 + 0][kl], T[cq + q * 4 + 1][kl],
                                   T[cq + q * 4 + 2][kl], T[cq + q * 4 + 3][kl]);
            *(float4*)(Wt + (size_t)kl * WT_LD + c0 + cq + q * 4) = v;
        }
    } else if (bid < TRB + DEGB) {
        int i = (bid - TRB) * 256 + t;
        if (i < NN) deg[i] = 1;   // self-loop
    } else {
        if (t == 0) nz = 0;
        __syncthreads();
        int c = 0;
        #pragma unroll
        for (int q = 0; q < 4; q++)
            if (ei[2 * (t * 4 + q) + 1] != 0) c++;
        if (c) atomicAdd(&nz, c);
        __syncthreads();
        if (t == 0) *flag = (nz == 0) ? 1 : 0;
    }
}

// ---------------- CSR build (by dst) ----------------
__global__ void k_hist(const int* __restrict__ ei, const int* __restrict__ flag,
                       int* __restrict__ deg) {
    int e = blockIdx.x * blockDim.x + threadIdx.x;
    if (e < NE) atomicAdd(&deg[ld_idx(ei, NE + e, *flag)], 1);
}

// wave-shuffle scan: 10 chunks x 3 barriers (vs 200 barriers before)
__global__ void k_scan(const int* __restrict__ deg, int* __restrict__ rowptr,
                       int* __restrict__ cursor) {
    __shared__ int wsum[16];
    __shared__ int carry;
    int t = threadIdx.x, lane = t & 63, wv = t >> 6;
    if (t == 0) carry = 0;
    __syncthreads();
    for (int base = 0; base < NN; base += 1024) {
        int i = base + t;
        int v = (i < NN) ? deg[i] : 0;
        int s = v;
        #pragma unroll
        for (int off = 1; off < 64; off <<= 1) {
            int u = __shfl_up(s, off, 64);
            if (lane >= off) s += u;
        }
        if (lane == 63) wsum[wv] = s;
        __syncthreads();
        if (t == 0) {
            int run = carry;
            #pragma unroll
            for (int j = 0; j < 16; j++) { int tmp = wsum[j]; wsum[j] = run; run += tmp; }
            carry = run;
        }
        __syncthreads();
        if (i < NN) { int ex = wsum[wv] + s - v; rowptr[i] = ex; cursor[i] = ex; }
        __syncthreads();   // protect wsum before next chunk overwrites
    }
    if (t == 0) rowptr[NN] = carry;
}

__global__ void k_scatter(const int* __restrict__ ei, const int* __restrict__ flag,
                          int* __restrict__ cursor, int* __restrict__ csr) {
    int e = blockIdx.x * blockDim.x + threadIdx.x;
    if (e < NE) {
        int mode = *flag;
        int d = ld_idx(ei, NE + e, mode);
        int pos = atomicAdd(&cursor[d], 1);
        csr[pos] = ld_idx(ei, e, mode);
    } else if (e < ET) {
        int n = e - NE;
        int pos = atomicAdd(&cursor[n], 1);
        csr[pos] = n;   // self-loop src == dst
    }
}

// ---- fused pair GEMM: Cl = A*Wl^T + bl, Cr = A*Wr^T + br (shared A tile) ----
// 64x64 tile, 256 threads, 4x4(+4x4) acc/thread. Per k: 32 FMA / 3 ds_read_b128
// (vs 2 GEMMs at 16 FMA / 2 reads) -> less LDS pressure, half the A traffic.
__global__ void __launch_bounds__(256) k_gemm12(
    const float* __restrict__ A,
    const float* __restrict__ Wl, const float* __restrict__ bl,
    const float* __restrict__ Wr, const float* __restrict__ br,
    float* __restrict__ Cl, float* __restrict__ Cr,
    int M, int Ndim, int K) {
    __shared__ float As[32][64];
    __shared__ float Ls[32][64];
    __shared__ float Rs[32][64];
    int t = threadIdx.x;
    int m0 = blockIdx.x * 64, n0 = blockIdx.y * 64;
    int lm = t >> 2;
    int kc = (t & 3) * 8;
    int tx = t & 15, ty = t >> 4;
    int rowA = m0 + lm;
    int rowW = n0 + lm;
    float accL[4][4] = {}, accR[4][4] = {};
    for (int kt = 0; kt < K; kt += 32) {
        float av[8];
        if (rowA < M) {
            const float* ap = A + (size_t)rowA * K + kt + kc;
            float4 p0 = *(const float4*)ap;
            float4 p1 = *(const float4*)(ap + 4);
            av[0] = p0.x; av[1] = p0.y; av[2] = p0.z; av[3] = p0.w;
            av[4] = p1.x; av[5] = p1.y; av[6] = p1.z; av[7] = p1.w;
        } else {
            #pragma unroll
            for (int j = 0; j < 8; j++) av[j] = 0.f;
        }
        const float* lp = Wl + (size_t)rowW * K + kt + kc;
        float4 l0 = *(const float4*)lp;
        float4 l1 = *(const float4*)(lp + 4);
        float lv[8] = {l0.x, l0.y, l0.z, l0.w, l1.x, l1.y, l1.z, l1.w};
        const float* rp = Wr + (size_t)rowW * K + kt + kc;
        float4 r0 = *(const float4*)rp;
        float4 r1 = *(const float4*)(rp + 4);
        float rv[8] = {r0.x, r0.y, r0.z, r0.w, r1.x, r1.y, r1.z, r1.w};
        #pragma unroll
        for (int j = 0; j < 8; j++) As[kc + j][lm] = av[j];
        #pragma unroll
        for (int j = 0; j < 8; j++) Ls[kc + j][lm] = lv[j];
        #pragma unroll
        for (int j = 0; j < 8; j++) Rs[kc + j][lm] = rv[j];
        __syncthreads();
        #pragma unroll
        for (int k = 0; k < 32; k++) {
            float4 a4 = *(const float4*)&As[k][ty * 4];
            float4 b4 = *(const float4*)&Ls[k][tx * 4];
            float4 c4 = *(const float4*)&Rs[k][tx * 4];
            float aa[4] = {a4.x, a4.y, a4.z, a4.w};
            float bb[4] = {b4.x, b4.y, b4.z, b4.w};
            float cc[4] = {c4.x, c4.y, c4.z, c4.w};
            #pragma unroll
            for (int i = 0; i < 4; i++)
                #pragma unroll
                for (int j = 0; j < 4; j++) {
                    accL[i][j] = fmaf(aa[i], bb[j], accL[i][j]);
                    accR[i][j] = fmaf(aa[i], cc[j], accR[i][j]);
                }
        }
        __syncthreads();
    }
    int col0 = n0 + tx * 4;
    float4 bvl = *(const float4*)&bl[col0];
    float4 bvr = *(const float4*)&br[col0];
    #pragma unroll
    for (int i = 0; i < 4; i++) {
        int r = m0 + ty * 4 + i;
        if (r < M) {
            float4 ol = make_float4(accL[i][0] + bvl.x, accL[i][1] + bvl.y,
                                    accL[i][2] + bvl.z, accL[i][3] + bvl.w);
            float4 orr = make_float4(accR[i][0] + bvr.x, accR[i][1] + bvr.y,
                                     accR[i][2] + bvr.z, accR[i][3] + bvr.w);
            *(float4*)&Cl[(size_t)r * Ndim + col0] = ol;
            *(float4*)&Cr[(size_t)r * Ndim + col0] = orr;
        }
    }
}

// ------- fused GATv2 layer 1: one wave per node, online softmax -------
// 2-deep row prefetch: per-edge serial chain (~220 cyc of shfl+exp) is shorter
// than L3/HBM load latency (~600-900 cyc); 2-ahead issue doubles the cover.
__global__ void __launch_bounds__(256) k_gat1(
    const float* __restrict__ xl, const float* __restrict__ xr,
    const float* __restrict__ att, const float* __restrict__ bias,
    const int* __restrict__ rowptr, const int* __restrict__ csr,
    float* __restrict__ out) {
    int wid = (blockIdx.x * blockDim.x + threadIdx.x) >> 6;
    int lane = threadIdx.x & 63;
    if (wid >= NN) return;
    int n = wid;
    int off = lane * 4;            // = (l>>4)*64 + 4*(l&15)
    const float4* xr4  = (const float4*)(xr + (size_t)n * 512 + off);
    const float4* att4 = (const float4*)(att + off);
    float4 xrA = xr4[0],  xrB = xr4[64];    // +256 floats
    float4 atA = att4[0], atB = att4[64];
    float4 accA = make_float4(0.f, 0.f, 0.f, 0.f);
    float4 accB = make_float4(0.f, 0.f, 0.f, 0.f);
    float lA = 0.f, lB = 0.f, mA = -1e30f, mB = -1e30f;

    int p0 = rowptr[n], p1 = rowptr[n + 1];
    int deg = p1 - p0;             // >= 1 (self-loop)
    float4 a0, b0, a1, b1;
    {
        const float4* p = (const float4*)(xl + (size_t)csr[p0] * 512 + off);
        a0 = p[0]; b0 = p[64];
    }
    if (deg > 1) {
        const float4* p = (const float4*)(xl + (size_t)csr[p0 + 1] * 512 + off);
        a1 = p[0]; b1 = p[64];
    } else { a1 = a0; b1 = b0; }
    for (int i = 0; i < deg; i++) {
        float4 cxa = a0, cxb = b0;
        a0 = a1; b0 = b1;
        if (i + 2 < deg) {
            const float4* np = (const float4*)(xl + (size_t)csr[p0 + i + 2] * 512 + off);
            a1 = np[0]; b1 = np[64];
        }
        // leaky(x+xr) . att, 4-channel partials
        float vA0 = cxa.x + xrA.x, vA1 = cxa.y + xrA.y,
              vA2 = cxa.z + xrA.z, vA3 = cxa.w + xrA.w;
        float vB0 = cxb.x + xrB.x, vB1 = cxb.y + xrB.y,
              vB2 = cxb.z + xrB.z, vB3 = cxb.w + xrB.w;
        vA0 = (vA0 > 0.f) ? vA0 : NEG * vA0;  vA1 = (vA1 > 0.f) ? vA1 : NEG * vA1;
        vA2 = (vA2 > 0.f) ? vA2 : NEG * vA2;  vA3 = (vA3 > 0.f) ? vA3 : NEG * vA3;
        vB0 = (vB0 > 0.f) ? vB0 : NEG * vB0;  vB1 = (vB1 > 0.f) ? vB1 : NEG * vB1;
        vB2 = (vB2 > 0.f) ? vB2 : NEG * vB2;  vB3 = (vB3 > 0.f) ? vB3 : NEG * vB3;
        float sA = vA0 * atA.x + vA1 * atA.y + vA2 * atA.z + vA3 * atA.w;
        float sB = vB0 * atB.x + vB1 * atB.y + vB2 * atB.z + vB3 * atB.w;
        #pragma unroll
        for (int m = 1; m <= 8; m <<= 1) {
            sA += __shfl_xor(sA, m, 64);
            sB += __shfl_xor(sB, m, 64);
        }
        // online softmax update, head A
        float mnA = fmaxf(mA, sA);
        float scA = __expf(mA - mnA), peA = __expf(sA - mnA);
        accA.x = accA.x * scA + peA * cxa.x;  accA.y = accA.y * scA + peA * cxa.y;
        accA.z = accA.z * scA + peA * cxa.z;  accA.w = accA.w * scA + peA * cxa.w;
        lA = lA * scA + peA;  mA = mnA;
        // head B
        float mnB = fmaxf(mB, sB);
        float scB = __expf(mB - mnB), peB = __expf(sB - mnB);
        accB.x = accB.x * scB + peB * cxb.x;  accB.y = accB.y * scB + peB * cxb.y;
        accB.z = accB.z * scB + peB * cxb.z;  accB.w = accB.w * scB + peB * cxb.w;
        lB = lB * scB + peB;  mB = mnB;
    }
    float rA = 1.f / (lA + 1e-16f), rB = 1.f / (lB + 1e-16f);
    float4 biA = *(const float4*)(bias + off);
    float4 biB = *(const float4*)(bias + off + 256);
    float4 oA = make_float4(fmaxf(accA.x * rA + biA.x, 0.f),
                            fmaxf(accA.y * rA + biA.y, 0.f),
                            fmaxf(accA.z * rA + biA.z, 0.f),
                            fmaxf(accA.w * rA + biA.w, 0.f));
    float4 oB = make_float4(fmaxf(accB.x * rB + biB.x, 0.f),
                            fmaxf(accB.y * rB + biB.y, 0.f),
                            fmaxf(accB.z * rB + biB.z, 0.f),
                            fmaxf(accB.w * rB + biB.w, 0.f));
    float4* op = (float4*)(out + (size_t)n * 512 + off);
    op[0]  = oA;      // ReLU applied (layer-1 activation)
    op[64] = oB;
}

// ------- fused GATv2 layer 2 (1 head, 64 ch): one wave per node -------
__global__ void __launch_bounds__(256) k_gat2(
    const float* __restrict__ xl, const float* __restrict__ xr,
    const float* __restrict__ att, const float* __restrict__ bias,
    const int* __restrict__ rowptr, const int* __restrict__ csr,
    float* __restrict__ out) {
    int wid = (blockIdx.x * blockDim.x + threadIdx.x) >> 6;
    int lane = threadIdx.x & 63;
    if (wid >= NN) return;
    int n = wid;
    float xrv = xr[(size_t)n * 64 + lane];
    float atv = att[lane];
    float acc = 0.f, lsum = 0.f, mmax = -1e30f;
    int p0 = rowptr[n], p1 = rowptr[n + 1];
    int deg = p1 - p0;
    float x0 = xl[(size_t)csr[p0] * 64 + lane];
    float x1 = (deg > 1) ? xl[(size_t)csr[p0 + 1] * 64 + lane] : x0;
    for (int i = 0; i < deg; i++) {
        float xs = x0;
        x0 = x1;
        if (i + 2 < deg) x1 = xl[(size_t)csr[p0 + i + 2] * 64 + lane];
        float v = xs + xrv;
        v = (v > 0.f) ? v : NEG * v;
        float sc = v * atv;
        #pragma unroll
        for (int off = 32; off > 0; off >>= 1)
            sc += __shfl_xor(sc, off, 64);
        float mn = fmaxf(mmax, sc);
        float scale = __expf(mmax - mn);
        float pe = __expf(sc - mn);
        acc = acc * scale + pe * xs;
        lsum = lsum * scale + pe;
        mmax = mn;
    }
    float o = acc / (lsum + 1e-16f) + bias[lane];
    out[(size_t)n * 64 + lane] = (o > 0.f) ? o : 0.f;   // ReLU after layer 2
}

// --- FC: out[10000,5000] = h2[10000,64] @ Wt + fc_b ---
// 16 rows/block (vs 8): halves Wt L2 traffic to ~800 MB -> FMA-bound
__global__ void __launch_bounds__(256) k_fc2(
    const float* __restrict__ A, const float* __restrict__ Wt,
    const float* __restrict__ bias, float* __restrict__ C) {
    __shared__ float As[64][FC_R];
    int t = threadIdx.x;
    int r0 = blockIdx.y * FC_R;
    int c0 = blockIdx.x * 1024 + t * 4;
    {
        int r = t >> 4, kq = (t & 15) * 4;
        float4 v = *(const float4*)(A + (size_t)(r0 + r) * 64 + kq);
        As[kq + 0][r] = v.x; As[kq + 1][r] = v.y;
        As[kq + 2][r] = v.z; As[kq + 3][r] = v.w;
    }
    __syncthreads();
    float acc[FC_R][4] = {};
    #pragma unroll 4
    for (int k = 0; k < 64; k++) {
        float4 wv = *(const float4*)(Wt + (size_t)k * WT_LD + c0);
        float4 a0 = *(const float4*)&As[k][0];
        float4 a1 = *(const float4*)&As[k][4];
        float4 a2 = *(const float4*)&As[k][8];
        float4 a3 = *(const float4*)&As[k][12];
        float ar[FC_R] = {a0.x, a0.y, a0.z, a0.w, a1.x, a1.y, a1.z, a1.w,
                          a2.x, a2.y, a2.z, a2.w, a3.x, a3.y, a3.z, a3.w};
        float wr[4] = {wv.x, wv.y, wv.z, wv.w};
        #pragma unroll
        for (int r = 0; r < FC_R; r++)
            #pragma unroll
            for (int j = 0; j < 4; j++)
                acc[r][j] = fmaf(ar[r], wr[j], acc[r][j]);
    }
    if (c0 < ODIM) {   // ODIM % 4 == 0: float4 chunk fully valid or fully out
        float4 bv = *(const float4*)(bias + c0);
        #pragma unroll
        for (int r = 0; r < FC_R; r++) {
            float4 o = make_float4(acc[r][0] + bv.x, acc[r][1] + bv.y,
                                   acc[r][2] + bv.z, acc[r][3] + bv.w);
            *(float4*)&C[(size_t)(r0 + r) * ODIM + c0] = o;
        }
    }
}

extern "C" void kernel_launch(void* const* d_in, const int* in_sizes, int n_in,
                              void* d_out, int out_size, void* d_ws, size_t ws_size,
                              hipStream_t stream) {
    const float* x     = (const float*)d_in[0];
    const int*   ei    = (const int*)d_in[1];
    const float* W1l   = (const float*)d_in[2];
    const float* b1l   = (const float*)d_in[3];
    const float* W1r   = (const float*)d_in[4];
    const float* b1r   = (const float*)d_in[5];
    const float* att1  = (const float*)d_in[6];
    const float* bias1 = (const float*)d_in[7];
    const float* W2l   = (const float*)d_in[8];
    const float* b2l   = (const float*)d_in[9];
    const float* W2r   = (const float*)d_in[10];
    const float* b2r   = (const float*)d_in[11];
    const float* att2  = (const float*)d_in[12];
    const float* bias2 = (const float*)d_in[13];
    const float* fcw   = (const float*)d_in[14];
    const float* fcb   = (const float*)d_in[15];
    float* out = (float*)d_out;

    char* p = (char*)d_ws;
    auto carve = [&](size_t bytes) {
        void* r = (void*)p;
        p += (bytes + 255) & ~(size_t)255;
        return r;
    };
    int* deg    = (int*)carve((size_t)NN * 4);
    int* rowptr = (int*)carve((size_t)(NN + 1) * 4);
    int* cursor = (int*)carve((size_t)NN * 4);
    int* csr    = (int*)carve((size_t)ET * 4);
    int* flag   = (int*)carve(256);
    float* Wt  = (float*)carve((size_t)64 * WT_LD * 4);
    float* xl1 = (float*)carve((size_t)NN * 512 * 4);
    float* xr1 = (float*)carve((size_t)NN * 512 * 4);
    float* h1  = (float*)carve((size_t)NN * 512 * 4);
    float* xl2 = xl1;                            // aliases: xl1/xr1 dead after k_gat1
    float* xr2 = xl1 + (size_t)NN * 64;
    float* h2  = xl1 + (size_t)NN * 128;

    // prep (transpose + deg init + format detect), then CSR by destination
    k_prep<<<PREPB, 256, 0, stream>>>(ei, flag, deg, fcw, Wt);
    k_hist<<<(NE + 255) / 256, 256, 0, stream>>>(ei, flag, deg);
    k_scan<<<1, 1024, 0, stream>>>(deg, rowptr, cursor);
    k_scatter<<<(ET + 255) / 256, 256, 0, stream>>>(ei, flag, cursor, csr);

    // layer 1: fused xl1/xr1 GEMM pair
    dim3 g1((NN + 63) / 64, 512 / 64);
    k_gemm12<<<g1, 256, 0, stream>>>(x, W1l, b1l, W1r, b1r, xl1, xr1, NN, 512, 512);
    k_gat1<<<(NN * 64 + 255) / 256, 256, 0, stream>>>(xl1, xr1, att1, bias1, rowptr, csr, h1);

    // layer 2: fused xl2/xr2 GEMM pair
    dim3 g2((NN + 63) / 64, 1);
    k_gemm12<<<g2, 256, 0, stream>>>(h1, W2l, b2l, W2r, b2r, xl2, xr2, NN, 64, 512);
    k_gat2<<<(NN * 64 + 255) / 256, 256, 0, stream>>>(xl2, xr2, att2, bias2, rowptr, csr, h2);

    // FC head: 5 col-blocks x 625 row-blocks
    dim3 g3((ODIM + 1023) / 1024, NN / FC_R);
    k_fc2<<<g3, 256, 0, stream>>>(h2, Wt, fcb, out);
}